// Round 3
// baseline (393.967 us; speedup 1.0000x reference)
//
#include <hip/hip_runtime.h>
#include <math.h>

#define HH 256
#define WW 256
#define CC 21
#define BB 16
#define HW (HH*WW)
#define CHW (CC*HW)
#define PHASE_OFF (BB*CHW)
#define AMP_OFF (PHASE_OFF + BB*HW)

static constexpr float DT = 0.1f;

typedef short short8 __attribute__((ext_vector_type(8)));
typedef float floatx4 __attribute__((ext_vector_type(4)));

__device__ __forceinline__ unsigned f2bf_bits(float f) {
    unsigned u = __builtin_bit_cast(unsigned, f);
    return (u + 0x7fffu + ((u >> 16) & 1u)) >> 16;   // RNE
}
__device__ __forceinline__ float bf2f(short s) {
    unsigned u = ((unsigned)(unsigned short)s) << 16;
    return __builtin_bit_cast(float, u);
}

// ---------- k0: build W_eff[9][96][32] bf16 and w2b[96] float4 in d_ws ----------
// W_eff[s][n][c] = effective conv weight for shift s=(ky*3+kx), hidden n, channel c.
__global__ __launch_bounds__(256)
void k0_prep(const float* __restrict__ w1w, const float* __restrict__ w1b,
             const float* __restrict__ w2w,
             short* __restrict__ weff, float4* __restrict__ w2b)
{
    const float SX[9] = {-1.f, 0.f, 1.f, -2.f, 0.f, 2.f, -1.f, 0.f, 1.f};
    const float SY[9] = {-1.f, -2.f, -1.f, 0.f, 0.f, 0.f, 1.f, 2.f, 1.f};
    const float LP[9] = {1.f, 2.f, 1.f, 2.f, -12.f, 2.f, 1.f, 2.f, 1.f};
    const int i = blockIdx.x * 256 + threadIdx.x;
    if (i < 9 * 96 * 32) {
        const int s = i / (96 * 32);
        const int rem = i - s * 96 * 32;
        const int n = rem >> 5, c = rem & 31;
        float v = 0.f;
        if (c < 21) {
            v = w1w[n * 84 + c] * ((s == 4) ? 1.f : 0.f)
              + w1w[n * 84 + 21 + 3 * c + 0] * SX[s]
              + w1w[n * 84 + 21 + 3 * c + 1] * SY[s]
              + w1w[n * 84 + 21 + 3 * c + 2] * LP[s];
        }
        weff[i] = (short)f2bf_bits(v);
    } else if (i < 9 * 96 * 32 + 96) {
        const int n = i - 9 * 96 * 32;
        w2b[n] = make_float4(w2w[n], w2w[96 + n], w2w[192 + n], w1b[n]);
    }
}

// ---------- k12: fused reaction + separable avg_pool5 + normalize + phase/amp + mod ----------
__global__ __launch_bounds__(256)
void k12_react(const float* __restrict__ x,
               const float* __restrict__ slow_w, const float* __restrict__ slow_b,
               const float* __restrict__ mod_w, const float* __restrict__ mod_b,
               const float* __restrict__ alpha_p, const float* __restrict__ beta_p,
               const float* __restrict__ omega_p, const float* __restrict__ K_p,
               const float* __restrict__ kappa_p,
               float* __restrict__ out)
{
    __shared__ float t[6][14][38];            // ch {3,4,5,15,16,17}, origin (Y0-3, X0-3)
    __shared__ float na[12][36], nb[12][36];  // new_a/new_b, origin (Y0-2, X0-2)
    __shared__ float ha[12][32], hb[12][32];  // horizontal 5-sums

    const int tx = threadIdx.x, ty = threadIdx.y;
    const int bb = blockIdx.z;
    const int X0 = blockIdx.x * 32, Y0 = blockIdx.y * 8;
    const int tid = ty * 32 + tx;

    const float alpha = alpha_p[0], beta = beta_p[0], omega = omega_p[0];
    const float Kc = K_p[0], kappa = kappa_p[0];

    const int chs[6] = {3, 4, 5, 15, 16, 17};
    for (int i = tid; i < 6 * 532; i += 256) {
        const int ch = i / 532;
        const int rem = i - ch * 532;
        const int r = rem / 38, c = rem - r * 38;
        const int gy = Y0 + r - 3, gx = X0 + c - 3;
        const bool inb = (gy >= 0) && (gy < HH) && (gx >= 0) && (gx < WW);
        t[ch][r][c] = inb ? x[((bb * CC + chs[ch]) * HH + gy) * WW + gx] : 0.f;
    }
    __syncthreads();

    for (int i = tid; i < 432; i += 256) {
        const int r2 = i / 36, c2 = i - r2 * 36;
        const int gy = Y0 + r2 - 2, gx = X0 + c2 - 2;
        float va = 0.f, vb = 0.f;
        if (gy >= 0 && gy < HH && gx >= 0 && gx < WW) {
            const int lr = r2 + 1, lc = c2 + 1;
            float lap3 = 0.f, lapA = 0.f, lapB = 0.f, emin = INFINITY;
            #pragma unroll
            for (int dy = -1; dy <= 1; dy++) {
                #pragma unroll
                for (int dx = -1; dx <= 1; dx++) {
                    const float lw = ((dy == 0 && dx == 0) ? -12.f
                                     : ((dy == 0 || dx == 0) ? 2.f : 1.f)) * (1.f / 12.f);
                    const float v3 = t[0][lr + dy][lc + dx];
                    lap3 = fmaf(lw, v3, lap3);
                    lapA = fmaf(lw, t[3][lr + dy][lc + dx], lapA);
                    lapB = fmaf(lw, t[4][lr + dy][lc + dx], lapB);
                    const bool nin = (gy + dy >= 0) && (gy + dy < HH) && (gx + dx >= 0) && (gx + dx < WW);
                    emin = fminf(emin, nin ? v3 : INFINITY);
                }
            }
            const float Q0 = t[0][lr][lc];
            const float Q1 = Q0 - emin, Q2 = lap3;
            const float Q3 = t[1][lr][lc], Q4 = t[2][lr][lc];
            const float I0 = slow_b[0] + slow_w[0] * Q0 + slow_w[1] * Q1 + slow_w[2] * Q2 + slow_w[3] * Q3 + slow_w[4] * Q4;
            const float I1 = slow_b[1] + slow_w[5] * Q0 + slow_w[6] * Q1 + slow_w[7] * Q2 + slow_w[8] * Q3 + slow_w[9] * Q4;
            const float a = t[3][lr][lc], b = t[4][lr][lc];
            va = a + DT * (-alpha * a + omega * b + Kc * lapA + I0);
            vb = b + DT * (-alpha * b - omega * a + Kc * lapB + I1);
        }
        na[r2][c2] = va;
        nb[r2][c2] = vb;
    }
    __syncthreads();

    // horizontal 5-sums: 12x32
    for (int i = tid; i < 384; i += 256) {
        const int r = i >> 5, c = i & 31;
        float sa = 0.f, sb = 0.f;
        #pragma unroll
        for (int dx = 0; dx < 5; dx++) { sa += na[r][c + dx]; sb += nb[r][c + dx]; }
        ha[r][c] = sa; hb[r][c] = sb;
    }
    __syncthreads();

    const int gy = Y0 + ty, gx = X0 + tx;
    const int lr = ty + 3, lc = tx + 3;

    float sa = 0.f, sb = 0.f;
    #pragma unroll
    for (int dy = 0; dy < 5; dy++) { sa += ha[ty + dy][tx]; sb += hb[ty + dy][tx]; }
    sa *= (1.f / 25.f); sb *= (1.f / 25.f);
    const float rho = sqrtf(sa * sa + sb * sb + 1e-6f);
    const float an = sa / rho, bn = sb / rho;
    const float a0 = na[ty + 2][tx + 2], b0 = nb[ty + 2][tx + 2];
    const float A2 = a0 + DT * (an - a0);
    const float B2 = b0 + DT * (bn - b0);

    float lapD = 0.f, lap3 = 0.f, emin = INFINITY;
    #pragma unroll
    for (int dy = -1; dy <= 1; dy++)
        #pragma unroll
        for (int dx = -1; dx <= 1; dx++) {
            const float lw = ((dy == 0 && dx == 0) ? -12.f
                             : ((dy == 0 || dx == 0) ? 2.f : 1.f)) * (1.f / 12.f);
            lapD = fmaf(lw, t[5][lr + dy][lc + dx], lapD);
            const float v3 = t[0][lr + dy][lc + dx];
            lap3 = fmaf(lw, v3, lap3);
            const bool nin = (gy + dy >= 0) && (gy + dy < HH) && (gx + dx >= 0) && (gx + dx < WW);
            emin = fminf(emin, nin ? v3 : INFINITY);
        }
    const float Q0 = t[0][lr][lc];
    const float I2 = slow_b[2] + slow_w[10] * Q0 + slow_w[11] * (Q0 - emin) + slow_w[12] * lap3
                   + slow_w[13] * t[1][lr][lc] + slow_w[14] * t[2][lr][lc];
    const float d0 = t[5][lr][lc];
    const float nd = d0 + DT * (-beta * d0 + kappa * lapD + I2);

    const float ph = sqrtf(A2 * A2 + B2 * B2 + 1e-6f);
    const float am = atan2f(B2, A2);

    const int po = gy * WW + gx;
    float* ob = out + bb * CHW;
    ob[15 * HW + po] = A2;
    ob[16 * HW + po] = B2;
    ob[17 * HW + po] = nd;
    #pragma unroll
    for (int j = 0; j < 3; j++)
        ob[(18 + j) * HW + po] = mod_b[j] + mod_w[j * 3 + 0] * A2 + mod_w[j * 3 + 1] * B2 + mod_w[j * 3 + 2] * nd;
    out[PHASE_OFF + bb * HW + po] = ph;
    out[AMP_OFF + bb * HW + po] = am;
}

// ---------- k3: implicit-GEMM perception+MLP, register H, shuffle readback ----------
__global__ __launch_bounds__(256, 4)
void k3_gene(const float* __restrict__ x, const float* __restrict__ noise,
             const short* __restrict__ weff, const float4* __restrict__ w2b,
             float* __restrict__ out)
{
    __shared__ __align__(16) short xt[10][34][40];  // [row y-1..y+8][col x-1..x+32][ch, 21..39 zero]

    const int tx = threadIdx.x, ty = threadIdx.y;
    const int tid = ty * 32 + tx;
    const int w = tid >> 6, lane = tid & 63;
    const int ln = lane & 15, kg = lane >> 4;
    const int bb = blockIdx.z;
    const int X0 = blockIdx.x * 32, Y0 = blockIdx.y * 8;
    const float* xb = x + bb * CHW;

    // ---- stage x tile -> bf16 LDS (wrap halo), zero-pad channels ----
    for (int idx = tid; idx < 340; idx += 256) {
        const int r = idx / 34, cc = idx - r * 34;
        const int gy = (Y0 + r - 1) & (HH - 1);
        const int gxx = (X0 + cc - 1) & (WW - 1);
        const float* src = xb + gy * WW + gxx;
        short* dst = &xt[r][cc][0];
        #pragma unroll
        for (int c = 0; c < 20; c += 2) {
            const unsigned lo = f2bf_bits(src[c * HW]);
            const unsigned hi = f2bf_bits(src[(c + 1) * HW]);
            *(unsigned*)(dst + c) = lo | (hi << 16);
        }
        *(unsigned*)(dst + 20) = f2bf_bits(src[20 * HW]);   // ch20 | ch21=0
        #pragma unroll
        for (int c = 22; c < 40; c += 2) *(unsigned*)(dst + c) = 0u;
    }
    __syncthreads();

    // ---- prefix copy, gene base, life/mask ----
    const int gy = Y0 + ty, gx = X0 + tx;
    const int po = gy * WW + gx;
    float* ob = out + bb * CHW;
    const float* xc = xb + po;
    #pragma unroll
    for (int c = 0; c < 12; c++) ob[c * HW + po] = xc[c * HW];
    const float c12 = xc[12 * HW], c13 = xc[13 * HW], c14 = xc[14 * HW];

    float m = -1e30f;
    #pragma unroll
    for (int ky = 0; ky < 3; ky++)
        #pragma unroll
        for (int kx = 0; kx < 3; kx++)
            m = fmaxf(m, bf2f(xt[ty + ky][tx + kx][3]));
    const float life = (m > 0.1f) ? 1.f : 0.f;
    const float g = floorf(noise[bb * HW + po] + 0.5f) * life;

    // ---- implicit GEMM: D[n][pixel] = sum_s W_eff[s] * x_shift(s) ----
    const short* xtf = &xt[0][0][0];
    int aoff[4];
    #pragma unroll
    for (int mt = 0; mt < 4; mt++)
        aoff[mt] = ((2 * w + (mt >> 1)) * 34 + (mt & 1) * 16 + ln) * 40 + kg * 8;

    float yj0[4] = {0.f, 0.f, 0.f, 0.f};
    float yj1[4] = {0.f, 0.f, 0.f, 0.f};
    float yj2[4] = {0.f, 0.f, 0.f, 0.f};

    #pragma unroll
    for (int pass = 0; pass < 2; pass++) {
        floatx4 acc[4][3];
        #pragma unroll
        for (int mt = 0; mt < 4; mt++)
            #pragma unroll
            for (int nt = 0; nt < 3; nt++)
                acc[mt][nt] = (floatx4){0.f, 0.f, 0.f, 0.f};

        #pragma unroll
        for (int s = 0; s < 9; s++) {
            const int soff = ((s / 3) * 34 + (s % 3)) * 40;
            short8 af[4];
            #pragma unroll
            for (int mt = 0; mt < 4; mt++)
                af[mt] = *(const short8*)(xtf + aoff[mt] + soff);
            short8 bf[3];
            #pragma unroll
            for (int nt = 0; nt < 3; nt++)
                bf[nt] = *(const short8*)(weff + ((size_t)(s * 96 + pass * 48 + nt * 16 + ln)) * 32 + kg * 8);
            #pragma unroll
            for (int nt = 0; nt < 3; nt++)
                #pragma unroll
                for (int mt = 0; mt < 4; mt++)
                    acc[mt][nt] = __builtin_amdgcn_mfma_f32_16x16x32_bf16(bf[nt], af[mt], acc[mt][nt], 0, 0, 0);
        }

        // readback: lane holds D[n = pass*48+nt*16+kg*4+r][pixel = w*64+mt*16+ln]
        #pragma unroll
        for (int nt = 0; nt < 3; nt++) {
            float4 wb[4];
            #pragma unroll
            for (int r = 0; r < 4; r++)
                wb[r] = w2b[pass * 48 + nt * 16 + kg * 4 + r];
            #pragma unroll
            for (int mt = 0; mt < 4; mt++)
                #pragma unroll
                for (int r = 0; r < 4; r++) {
                    const float h = fmaxf(acc[mt][nt][r] + wb[r].w, 0.f);
                    yj0[mt] = fmaf(h, wb[r].x, yj0[mt]);
                    yj1[mt] = fmaf(h, wb[r].y, yj1[mt]);
                    yj2[mt] = fmaf(h, wb[r].z, yj2[mt]);
                }
        }
    }

    // ---- cross-kg reduce; lane keeps result when mt == kg (pixel == tid) ----
    float fy0 = 0.f, fy1 = 0.f, fy2 = 0.f;
    #pragma unroll
    for (int mt = 0; mt < 4; mt++) {
        float t0 = yj0[mt] + __shfl_xor(yj0[mt], 16, 64);
        t0 += __shfl_xor(t0, 32, 64);
        float t1 = yj1[mt] + __shfl_xor(yj1[mt], 16, 64);
        t1 += __shfl_xor(t1, 32, 64);
        float t2 = yj2[mt] + __shfl_xor(yj2[mt], 16, 64);
        t2 += __shfl_xor(t2, 32, 64);
        if (kg == mt) { fy0 = t0; fy1 = t1; fy2 = t2; }
    }

    ob[12 * HW + po] = c12 + fy0 * g;
    ob[13 * HW + po] = c13 + fy1 * g;
    ob[14 * HW + po] = c14 + fy2 * g;
}

extern "C" void kernel_launch(void* const* d_in, const int* in_sizes, int n_in,
                              void* d_out, int out_size, void* d_ws, size_t ws_size,
                              hipStream_t stream)
{
    const float* x      = (const float*)d_in[0];
    const float* noise  = (const float*)d_in[1];
    const float* w1w    = (const float*)d_in[2];
    const float* w1b    = (const float*)d_in[3];
    const float* w2w    = (const float*)d_in[4];
    const float* sloww  = (const float*)d_in[5];
    const float* slowb  = (const float*)d_in[6];
    const float* modw   = (const float*)d_in[7];
    const float* modb   = (const float*)d_in[8];
    const float* alphap = (const float*)d_in[9];
    const float* betap  = (const float*)d_in[10];
    const float* omegap = (const float*)d_in[11];
    const float* Kp     = (const float*)d_in[12];
    const float* kappap = (const float*)d_in[13];
    float* out = (float*)d_out;

    short* weff = (short*)d_ws;                      // 9*96*32*2 = 55296 B
    float4* w2b = (float4*)((char*)d_ws + 55296);    // 96*16 = 1536 B

    dim3 blk(32, 8, 1);
    dim3 grd(WW / 32, HH / 8, BB);

    k0_prep<<<dim3(109), dim3(256), 0, stream>>>(w1w, w1b, w2w, weff, w2b);
    k12_react<<<grd, blk, 0, stream>>>(x, sloww, slowb, modw, modb,
                                       alphap, betap, omegap, Kp, kappap, out);
    k3_gene<<<grd, blk, 0, stream>>>(x, noise, weff, w2b, out);
}

// Round 4
// 307.039 us; speedup vs baseline: 1.2831x; 1.2831x over previous
//
#include <hip/hip_runtime.h>
#include <math.h>

#define HH 256
#define WW 256
#define CC 21
#define BB 16
#define HW (HH*WW)
#define CHW (CC*HW)
#define PHASE_OFF (BB*CHW)
#define AMP_OFF (PHASE_OFF + BB*HW)

static constexpr float DT = 0.1f;

typedef short short8 __attribute__((ext_vector_type(8)));
typedef float floatx4 __attribute__((ext_vector_type(4)));

__device__ __forceinline__ unsigned f2bf_bits(float f) {
    unsigned u = __builtin_bit_cast(unsigned, f);
    return (u + 0x7fffu + ((u >> 16) & 1u)) >> 16;   // RNE
}
__device__ __forceinline__ float bf2f(short s) {
    unsigned u = ((unsigned)(unsigned short)s) << 16;
    return __builtin_bit_cast(float, u);
}

// ---------- k0: build W_eff[9][96][32] bf16 and w2b[96] float4 in d_ws ----------
__global__ __launch_bounds__(256)
void k0_prep(const float* __restrict__ w1w, const float* __restrict__ w1b,
             const float* __restrict__ w2w,
             short* __restrict__ weff, float4* __restrict__ w2b)
{
    const float SX[9] = {-1.f, 0.f, 1.f, -2.f, 0.f, 2.f, -1.f, 0.f, 1.f};
    const float SY[9] = {-1.f, -2.f, -1.f, 0.f, 0.f, 0.f, 1.f, 2.f, 1.f};
    const float LP[9] = {1.f, 2.f, 1.f, 2.f, -12.f, 2.f, 1.f, 2.f, 1.f};
    const int i = blockIdx.x * 256 + threadIdx.x;
    if (i < 9 * 96 * 32) {
        const int s = i / (96 * 32);
        const int rem = i - s * 96 * 32;
        const int n = rem >> 5, c = rem & 31;
        float v = 0.f;
        if (c < 21) {
            v = w1w[n * 84 + c] * ((s == 4) ? 1.f : 0.f)
              + w1w[n * 84 + 21 + 3 * c + 0] * SX[s]
              + w1w[n * 84 + 21 + 3 * c + 1] * SY[s]
              + w1w[n * 84 + 21 + 3 * c + 2] * LP[s];
        }
        weff[i] = (short)f2bf_bits(v);
    } else if (i < 9 * 96 * 32 + 96) {
        const int n = i - 9 * 96 * 32;
        w2b[n] = make_float4(w2w[n], w2w[96 + n], w2w[192 + n], w1b[n]);
    }
}

// ---------- k12: fused reaction + separable avg_pool5 + normalize + phase/amp + mod ----------
__global__ __launch_bounds__(256)
void k12_react(const float* __restrict__ x,
               const float* __restrict__ slow_w, const float* __restrict__ slow_b,
               const float* __restrict__ mod_w, const float* __restrict__ mod_b,
               const float* __restrict__ alpha_p, const float* __restrict__ beta_p,
               const float* __restrict__ omega_p, const float* __restrict__ K_p,
               const float* __restrict__ kappa_p,
               float* __restrict__ out)
{
    __shared__ float t[6][14][38];            // ch {3,4,5,15,16,17}, origin (Y0-3, X0-3)
    __shared__ float na[12][36], nb[12][36];  // new_a/new_b, origin (Y0-2, X0-2)
    __shared__ float ha[12][32], hb[12][32];  // horizontal 5-sums

    const int tx = threadIdx.x, ty = threadIdx.y;
    const int bb = blockIdx.z;
    const int X0 = blockIdx.x * 32, Y0 = blockIdx.y * 8;
    const int tid = ty * 32 + tx;

    const float alpha = alpha_p[0], beta = beta_p[0], omega = omega_p[0];
    const float Kc = K_p[0], kappa = kappa_p[0];

    // stage 6 channels, 14x38, zero-filled OOB — channels statically unrolled (no scratch)
    const float* xb = x + (size_t)bb * CHW;
    for (int i = tid; i < 532; i += 256) {
        const int r = i / 38, c = i - r * 38;
        const int gy = Y0 + r - 3, gx = X0 + c - 3;
        const bool inb = (gy >= 0) && (gy < HH) && (gx >= 0) && (gx < WW);
        const int off = gy * WW + gx;
        t[0][r][c] = inb ? xb[3  * HW + off] : 0.f;
        t[1][r][c] = inb ? xb[4  * HW + off] : 0.f;
        t[2][r][c] = inb ? xb[5  * HW + off] : 0.f;
        t[3][r][c] = inb ? xb[15 * HW + off] : 0.f;
        t[4][r][c] = inb ? xb[16 * HW + off] : 0.f;
        t[5][r][c] = inb ? xb[17 * HW + off] : 0.f;
    }
    __syncthreads();

    for (int i = tid; i < 432; i += 256) {
        const int r2 = i / 36, c2 = i - r2 * 36;
        const int gy = Y0 + r2 - 2, gx = X0 + c2 - 2;
        float va = 0.f, vb = 0.f;
        if (gy >= 0 && gy < HH && gx >= 0 && gx < WW) {
            const int lr = r2 + 1, lc = c2 + 1;
            float lap3 = 0.f, lapA = 0.f, lapB = 0.f, emin = INFINITY;
            #pragma unroll
            for (int dy = -1; dy <= 1; dy++) {
                #pragma unroll
                for (int dx = -1; dx <= 1; dx++) {
                    const float lw = ((dy == 0 && dx == 0) ? -12.f
                                     : ((dy == 0 || dx == 0) ? 2.f : 1.f)) * (1.f / 12.f);
                    const float v3 = t[0][lr + dy][lc + dx];
                    lap3 = fmaf(lw, v3, lap3);
                    lapA = fmaf(lw, t[3][lr + dy][lc + dx], lapA);
                    lapB = fmaf(lw, t[4][lr + dy][lc + dx], lapB);
                    const bool nin = (gy + dy >= 0) && (gy + dy < HH) && (gx + dx >= 0) && (gx + dx < WW);
                    emin = fminf(emin, nin ? v3 : INFINITY);
                }
            }
            const float Q0 = t[0][lr][lc];
            const float Q1 = Q0 - emin, Q2 = lap3;
            const float Q3 = t[1][lr][lc], Q4 = t[2][lr][lc];
            const float I0 = slow_b[0] + slow_w[0] * Q0 + slow_w[1] * Q1 + slow_w[2] * Q2 + slow_w[3] * Q3 + slow_w[4] * Q4;
            const float I1 = slow_b[1] + slow_w[5] * Q0 + slow_w[6] * Q1 + slow_w[7] * Q2 + slow_w[8] * Q3 + slow_w[9] * Q4;
            const float a = t[3][lr][lc], b = t[4][lr][lc];
            va = a + DT * (-alpha * a + omega * b + Kc * lapA + I0);
            vb = b + DT * (-alpha * b - omega * a + Kc * lapB + I1);
        }
        na[r2][c2] = va;
        nb[r2][c2] = vb;
    }
    __syncthreads();

    // horizontal 5-sums: 12x32
    for (int i = tid; i < 384; i += 256) {
        const int r = i >> 5, c = i & 31;
        float sa = 0.f, sb = 0.f;
        #pragma unroll
        for (int dx = 0; dx < 5; dx++) { sa += na[r][c + dx]; sb += nb[r][c + dx]; }
        ha[r][c] = sa; hb[r][c] = sb;
    }
    __syncthreads();

    const int gy = Y0 + ty, gx = X0 + tx;
    const int lr = ty + 3, lc = tx + 3;

    float sa = 0.f, sb = 0.f;
    #pragma unroll
    for (int dy = 0; dy < 5; dy++) { sa += ha[ty + dy][tx]; sb += hb[ty + dy][tx]; }
    sa *= (1.f / 25.f); sb *= (1.f / 25.f);
    const float rho = sqrtf(sa * sa + sb * sb + 1e-6f);
    const float an = sa / rho, bn = sb / rho;
    const float a0 = na[ty + 2][tx + 2], b0 = nb[ty + 2][tx + 2];
    const float A2 = a0 + DT * (an - a0);
    const float B2 = b0 + DT * (bn - b0);

    float lapD = 0.f, lap3 = 0.f, emin = INFINITY;
    #pragma unroll
    for (int dy = -1; dy <= 1; dy++)
        #pragma unroll
        for (int dx = -1; dx <= 1; dx++) {
            const float lw = ((dy == 0 && dx == 0) ? -12.f
                             : ((dy == 0 || dx == 0) ? 2.f : 1.f)) * (1.f / 12.f);
            lapD = fmaf(lw, t[5][lr + dy][lc + dx], lapD);
            const float v3 = t[0][lr + dy][lc + dx];
            lap3 = fmaf(lw, v3, lap3);
            const bool nin = (gy + dy >= 0) && (gy + dy < HH) && (gx + dx >= 0) && (gx + dx < WW);
            emin = fminf(emin, nin ? v3 : INFINITY);
        }
    const float Q0 = t[0][lr][lc];
    const float I2 = slow_b[2] + slow_w[10] * Q0 + slow_w[11] * (Q0 - emin) + slow_w[12] * lap3
                   + slow_w[13] * t[1][lr][lc] + slow_w[14] * t[2][lr][lc];
    const float d0 = t[5][lr][lc];
    const float nd = d0 + DT * (-beta * d0 + kappa * lapD + I2);

    const float ph = sqrtf(A2 * A2 + B2 * B2 + 1e-6f);
    const float am = atan2f(B2, A2);

    const int po = gy * WW + gx;
    float* ob = out + bb * CHW;
    ob[15 * HW + po] = A2;
    ob[16 * HW + po] = B2;
    ob[17 * HW + po] = nd;
    #pragma unroll
    for (int j = 0; j < 3; j++)
        ob[(18 + j) * HW + po] = mod_b[j] + mod_w[j * 3 + 0] * A2 + mod_w[j * 3 + 1] * B2 + mod_w[j * 3 + 2] * nd;
    out[PHASE_OFF + bb * HW + po] = ph;
    out[AMP_OFF + bb * HW + po] = am;
}

// ---------- k3: implicit-GEMM perception+MLP, register H, shuffle readback ----------
__global__ __launch_bounds__(256, 3)   // (256,4) caused scratch spill @64 VGPR: 800MB HBM traffic
void k3_gene(const float* __restrict__ x, const float* __restrict__ noise,
             const short* __restrict__ weff, const float4* __restrict__ w2b,
             float* __restrict__ out)
{
    __shared__ __align__(16) short xt[10][34][40];  // [row y-1..y+8][col x-1..x+32][ch, 21..39 zero]

    const int tx = threadIdx.x, ty = threadIdx.y;
    const int tid = ty * 32 + tx;
    const int w = tid >> 6, lane = tid & 63;
    const int ln = lane & 15, kg = lane >> 4;
    const int bb = blockIdx.z;
    const int X0 = blockIdx.x * 32, Y0 = blockIdx.y * 8;
    const float* xb = x + bb * CHW;

    // ---- stage x tile -> bf16 LDS (wrap halo), zero-pad channels ----
    for (int idx = tid; idx < 340; idx += 256) {
        const int r = idx / 34, cc = idx - r * 34;
        const int gy = (Y0 + r - 1) & (HH - 1);
        const int gxx = (X0 + cc - 1) & (WW - 1);
        const float* src = xb + gy * WW + gxx;
        short* dst = &xt[r][cc][0];
        #pragma unroll
        for (int c = 0; c < 20; c += 2) {
            const unsigned lo = f2bf_bits(src[c * HW]);
            const unsigned hi = f2bf_bits(src[(c + 1) * HW]);
            *(unsigned*)(dst + c) = lo | (hi << 16);
        }
        *(unsigned*)(dst + 20) = f2bf_bits(src[20 * HW]);   // ch20 | ch21=0
        #pragma unroll
        for (int c = 22; c < 40; c += 2) *(unsigned*)(dst + c) = 0u;
    }
    __syncthreads();

    // ---- prefix copy, gene base, life/mask ----
    const int gy = Y0 + ty, gx = X0 + tx;
    const int po = gy * WW + gx;
    float* ob = out + bb * CHW;
    const float* xc = xb + po;
    #pragma unroll
    for (int c = 0; c < 12; c++) ob[c * HW + po] = xc[c * HW];
    const float c12 = xc[12 * HW], c13 = xc[13 * HW], c14 = xc[14 * HW];

    float m = -1e30f;
    #pragma unroll
    for (int ky = 0; ky < 3; ky++)
        #pragma unroll
        for (int kx = 0; kx < 3; kx++)
            m = fmaxf(m, bf2f(xt[ty + ky][tx + kx][3]));
    const float life = (m > 0.1f) ? 1.f : 0.f;
    const float g = floorf(noise[bb * HW + po] + 0.5f) * life;

    // ---- implicit GEMM: D[n][pixel] = sum_s W_eff[s] * x_shift(s) ----
    const short* xtf = &xt[0][0][0];
    int aoff[4];
    #pragma unroll
    for (int mt = 0; mt < 4; mt++)
        aoff[mt] = ((2 * w + (mt >> 1)) * 34 + (mt & 1) * 16 + ln) * 40 + kg * 8;

    float yj0[4] = {0.f, 0.f, 0.f, 0.f};
    float yj1[4] = {0.f, 0.f, 0.f, 0.f};
    float yj2[4] = {0.f, 0.f, 0.f, 0.f};

    #pragma unroll
    for (int pass = 0; pass < 2; pass++) {
        floatx4 acc[4][3];
        #pragma unroll
        for (int mt = 0; mt < 4; mt++)
            #pragma unroll
            for (int nt = 0; nt < 3; nt++)
                acc[mt][nt] = (floatx4){0.f, 0.f, 0.f, 0.f};

        #pragma unroll
        for (int s = 0; s < 9; s++) {
            const int soff = ((s / 3) * 34 + (s % 3)) * 40;
            short8 af[4];
            #pragma unroll
            for (int mt = 0; mt < 4; mt++)
                af[mt] = *(const short8*)(xtf + aoff[mt] + soff);
            short8 bf[3];
            #pragma unroll
            for (int nt = 0; nt < 3; nt++)
                bf[nt] = *(const short8*)(weff + ((size_t)(s * 96 + pass * 48 + nt * 16 + ln)) * 32 + kg * 8);
            #pragma unroll
            for (int nt = 0; nt < 3; nt++)
                #pragma unroll
                for (int mt = 0; mt < 4; mt++)
                    acc[mt][nt] = __builtin_amdgcn_mfma_f32_16x16x32_bf16(bf[nt], af[mt], acc[mt][nt], 0, 0, 0);
        }

        // readback: lane holds D[n = pass*48+nt*16+kg*4+r][pixel = w*64+mt*16+ln]
        #pragma unroll
        for (int nt = 0; nt < 3; nt++) {
            float4 wb[4];
            #pragma unroll
            for (int r = 0; r < 4; r++)
                wb[r] = w2b[pass * 48 + nt * 16 + kg * 4 + r];
            #pragma unroll
            for (int mt = 0; mt < 4; mt++)
                #pragma unroll
                for (int r = 0; r < 4; r++) {
                    const float h = fmaxf(acc[mt][nt][r] + wb[r].w, 0.f);
                    yj0[mt] = fmaf(h, wb[r].x, yj0[mt]);
                    yj1[mt] = fmaf(h, wb[r].y, yj1[mt]);
                    yj2[mt] = fmaf(h, wb[r].z, yj2[mt]);
                }
        }
    }

    // ---- cross-kg reduce; lane keeps result when mt == kg (pixel == tid) ----
    float fy0 = 0.f, fy1 = 0.f, fy2 = 0.f;
    #pragma unroll
    for (int mt = 0; mt < 4; mt++) {
        float t0 = yj0[mt] + __shfl_xor(yj0[mt], 16, 64);
        t0 += __shfl_xor(t0, 32, 64);
        float t1 = yj1[mt] + __shfl_xor(yj1[mt], 16, 64);
        t1 += __shfl_xor(t1, 32, 64);
        float t2 = yj2[mt] + __shfl_xor(yj2[mt], 16, 64);
        t2 += __shfl_xor(t2, 32, 64);
        if (kg == mt) { fy0 = t0; fy1 = t1; fy2 = t2; }
    }

    ob[12 * HW + po] = c12 + fy0 * g;
    ob[13 * HW + po] = c13 + fy1 * g;
    ob[14 * HW + po] = c14 + fy2 * g;
}

extern "C" void kernel_launch(void* const* d_in, const int* in_sizes, int n_in,
                              void* d_out, int out_size, void* d_ws, size_t ws_size,
                              hipStream_t stream)
{
    const float* x      = (const float*)d_in[0];
    const float* noise  = (const float*)d_in[1];
    const float* w1w    = (const float*)d_in[2];
    const float* w1b    = (const float*)d_in[3];
    const float* w2w    = (const float*)d_in[4];
    const float* sloww  = (const float*)d_in[5];
    const float* slowb  = (const float*)d_in[6];
    const float* modw   = (const float*)d_in[7];
    const float* modb   = (const float*)d_in[8];
    const float* alphap = (const float*)d_in[9];
    const float* betap  = (const float*)d_in[10];
    const float* omegap = (const float*)d_in[11];
    const float* Kp     = (const float*)d_in[12];
    const float* kappap = (const float*)d_in[13];
    float* out = (float*)d_out;

    short* weff = (short*)d_ws;                      // 9*96*32*2 = 55296 B
    float4* w2b = (float4*)((char*)d_ws + 55296);    // 96*16 = 1536 B

    dim3 blk(32, 8, 1);
    dim3 grd(WW / 32, HH / 8, BB);

    k0_prep<<<dim3(109), dim3(256), 0, stream>>>(w1w, w1b, w2w, weff, w2b);
    k12_react<<<grd, blk, 0, stream>>>(x, sloww, slowb, modw, modb,
                                       alphap, betap, omegap, Kp, kappap, out);
    k3_gene<<<grd, blk, 0, stream>>>(x, noise, weff, w2b, out);
}